// Round 1
// baseline (165.623 us; speedup 1.0000x reference)
//
#include <hip/hip_runtime.h>
#include <stdint.h>

#define HIDDEN 768
#define EMBED  512
#define BATCH  16
#define SEQ    512
#define NWORDS (BATCH*SEQ)      // 8192
#define PAD_FLAT_IDX 2047       // flat index of words[0, 511, 3]
#define NEG_SLOPE 0.1f

__device__ __forceinline__ unsigned short f2bf(float f) {
    // round-to-nearest-even fp32 -> bf16 (inputs are finite; NaN path irrelevant)
    unsigned int x = __float_as_uint(f);
    unsigned int r = x + 0x7fffu + ((x >> 16) & 1u);
    return (unsigned short)(r >> 16);
}

// ---------------------------------------------------------------------------
// Kernel 1: per-batch stable-compaction scan.
// dest[b*SEQ+s] = global output row this word's pooled vector goes to:
//   valid   -> b*SEQ + (#valid words before s)           (stable compaction)
//   invalid -> b*SEQ + lens[b] + (#invalid words before s)  (gets pad_vec)
// ---------------------------------------------------------------------------
__global__ __launch_bounds__(512) void scan_kernel(const int* __restrict__ words,
                                                   int* __restrict__ dest) {
    int b = blockIdx.x;
    int s = threadIdx.x;          // 0..511
    int idx = b * SEQ + s;
    int4 w4 = ((const int4*)words)[idx];
    bool valid = (w4.x | w4.y | w4.z | w4.w) != 0;

    unsigned long long m = __ballot(valid);
    int lane = s & 63;
    int wave = s >> 6;            // 0..7
    int wpre = __popcll(m & ((1ull << lane) - 1ull));
    __shared__ int wsum[8];
    if (lane == 0) wsum[wave] = __popcll(m);
    __syncthreads();
    int off = 0, tot = 0;
#pragma unroll
    for (int i = 0; i < 8; ++i) {
        int t = wsum[i];
        if (i < wave) off += t;
        tot += t;
    }
    int vp = off + wpre;                       // # valid before s
    int d = valid ? vp : (tot + (s - vp));     // stable; bijective over [0,SEQ)
    dest[idx] = b * SEQ + d;
}

// ---------------------------------------------------------------------------
// Kernel 2: gather 4 embedding rows, masked mean-pool, scatter to compacted
// row as bf16. Invalid words (cnt==0) write pad_vec = embed[words[0,-1,-1]].
// One block per word; 192 threads x float4 covers HIDDEN=768.
// ---------------------------------------------------------------------------
__global__ __launch_bounds__(192) void pool_kernel(const int* __restrict__ words,
                                                   const float* __restrict__ table,
                                                   const int* __restrict__ dest,
                                                   unsigned short* __restrict__ xseq) {
    int word = blockIdx.x;        // 0..8191
    int t = threadIdx.x;          // 0..191
    int4 w4 = ((const int4*)words)[word];
    int cnt = (w4.x != 0) + (w4.y != 0) + (w4.z != 0) + (w4.w != 0);

    float ax = 0.f, ay = 0.f, az = 0.f, aw = 0.f;
    if (cnt == 0) {
        int pid = words[PAD_FLAT_IDX];
        float4 v = ((const float4*)(table + (size_t)pid * HIDDEN))[t];
        ax = v.x; ay = v.y; az = v.z; aw = v.w;
    } else {
        if (w4.x != 0) { float4 v = ((const float4*)(table + (size_t)w4.x * HIDDEN))[t]; ax += v.x; ay += v.y; az += v.z; aw += v.w; }
        if (w4.y != 0) { float4 v = ((const float4*)(table + (size_t)w4.y * HIDDEN))[t]; ax += v.x; ay += v.y; az += v.z; aw += v.w; }
        if (w4.z != 0) { float4 v = ((const float4*)(table + (size_t)w4.z * HIDDEN))[t]; ax += v.x; ay += v.y; az += v.z; aw += v.w; }
        if (w4.w != 0) { float4 v = ((const float4*)(table + (size_t)w4.w * HIDDEN))[t]; ax += v.x; ay += v.y; az += v.z; aw += v.w; }
        float inv = 1.0f / (float)cnt;
        ax *= inv; ay *= inv; az *= inv; aw *= inv;
    }
    ushort4 o;
    o.x = f2bf(ax); o.y = f2bf(ay); o.z = f2bf(az); o.w = f2bf(aw);
    int drow = dest[word];
    ((ushort4*)(xseq + (size_t)drow * HIDDEN))[t] = o;
}

// ---------------------------------------------------------------------------
// Kernel 3: w_ffn [768,512] fp32 row-major -> wt [512,768] bf16 (N-major, so
// the GEMM stages B exactly like A: rows with K contiguous).
// ---------------------------------------------------------------------------
__global__ __launch_bounds__(256) void wt_kernel(const float* __restrict__ w,
                                                 unsigned short* __restrict__ wt) {
    __shared__ float tile[32][33];   // +1 pad: conflict-free transpose
    int k0 = blockIdx.x * 32;        // 24 blocks
    int n0 = blockIdx.y * 32;        // 16 blocks
    int tc = threadIdx.x & 31;
    int tr = threadIdx.x >> 5;       // 0..7
#pragma unroll
    for (int i = 0; i < 4; ++i) {
        int r = tr + i * 8;
        tile[r][tc] = w[(size_t)(k0 + r) * EMBED + n0 + tc];
    }
    __syncthreads();
#pragma unroll
    for (int i = 0; i < 4; ++i) {
        int r = tr + i * 8;          // n offset within tile
        wt[(size_t)(n0 + r) * HIDDEN + k0 + tc] = f2bf(tile[tc][r]);
    }
}

// ---------------------------------------------------------------------------
// Kernel 4: C = leaky_relu(A @ Bt^T + bias). A=[8192,768] bf16, Bt=[512,768]
// bf16 (N-major), out fp32 [8192,512].
// Tile 64(M) x 128(N) x 32(K); 256 threads = 4 waves in 2x2; each wave does
// 2x4 MFMA 16x16x32 tiles. global_load_lds width=16 staging (m97 pattern).
// Grid 128x4 = 512 blocks -> 2 blocks/CU.
// ---------------------------------------------------------------------------
typedef __attribute__((ext_vector_type(8))) short bf16x8;
typedef __attribute__((ext_vector_type(4))) float f32x4;

__device__ __forceinline__ void load_lds16(const void* g, void* l) {
    __builtin_amdgcn_global_load_lds(
        (const __attribute__((address_space(1))) unsigned int*)g,
        (__attribute__((address_space(3))) unsigned int*)l,
        16, 0, 0);
}

#define BM 64
#define BN 128
#define BK 32

__global__ __launch_bounds__(256) void gemm_kernel(const unsigned short* __restrict__ A,
                                                   const unsigned short* __restrict__ Bt,
                                                   const float* __restrict__ bias,
                                                   float* __restrict__ out) {
    __shared__ unsigned short sA[BM * BK];   // 4 KB
    __shared__ unsigned short sB[BN * BK];   // 8 KB

    int tid  = threadIdx.x;
    int m0   = blockIdx.x * BM;
    int n0   = blockIdx.y * BN;
    int wave = tid >> 6;
    int lane = tid & 63;
    int wr   = wave >> 1;        // 0..1: 32-row slab
    int wc   = wave & 1;         // 0..1: 64-col slab
    int quad = lane >> 4;        // 0..3
    int l16  = lane & 15;

    f32x4 acc[2][4] = {};

    // staging map: idx -> row idx>>2, k (idx&3)*8; LDS dest = idx*16B
    int r_s = tid >> 2;          // 0..63
    int k_s = (tid & 3) * 8;

    const unsigned short* ga = A  + (size_t)(m0 + r_s) * HIDDEN + k_s;
    const unsigned short* gb0 = Bt + (size_t)(n0 + r_s) * HIDDEN + k_s;
    const unsigned short* gb1 = Bt + (size_t)(n0 + r_s + 64) * HIDDEN + k_s;

    for (int k0 = 0; k0 < HIDDEN; k0 += BK) {
        load_lds16(ga + k0,  &sA[tid * 8]);
        load_lds16(gb0 + k0, &sB[tid * 8]);
        load_lds16(gb1 + k0, &sB[(256 + tid) * 8]);
        __syncthreads();

        bf16x8 af[2], bf[4];
#pragma unroll
        for (int mt = 0; mt < 2; ++mt)
            af[mt] = *(const bf16x8*)&sA[(wr * 32 + mt * 16 + l16) * BK + quad * 8];
#pragma unroll
        for (int nt = 0; nt < 4; ++nt)
            bf[nt] = *(const bf16x8*)&sB[(wc * 64 + nt * 16 + l16) * BK + quad * 8];

#pragma unroll
        for (int mt = 0; mt < 2; ++mt)
#pragma unroll
            for (int nt = 0; nt < 4; ++nt)
                acc[mt][nt] = __builtin_amdgcn_mfma_f32_16x16x32_bf16(
                    af[mt], bf[nt], acc[mt][nt], 0, 0, 0);
        __syncthreads();
    }

    // epilogue: D row = quad*4+r, col = l16 (m89/m91-verified layout)
#pragma unroll
    for (int nt = 0; nt < 4; ++nt) {
        int col = n0 + wc * 64 + nt * 16 + l16;
        float bv = bias[col];
#pragma unroll
        for (int mt = 0; mt < 2; ++mt) {
            int rbase = m0 + wr * 32 + mt * 16 + quad * 4;
#pragma unroll
            for (int r = 0; r < 4; ++r) {
                float v = acc[mt][nt][r] + bv;
                v = (v > 0.f) ? v : v * NEG_SLOPE;
                out[(size_t)(rbase + r) * EMBED + col] = v;
            }
        }
    }
}

// ---------------------------------------------------------------------------
extern "C" void kernel_launch(void* const* d_in, const int* in_sizes, int n_in,
                              void* d_out, int out_size, void* d_ws, size_t ws_size,
                              hipStream_t stream) {
    (void)in_sizes; (void)n_in; (void)out_size; (void)ws_size;
    const int*   words = (const int*)d_in[0];
    const float* table = (const float*)d_in[1];
    const float* wffn  = (const float*)d_in[2];
    const float* bffn  = (const float*)d_in[3];
    float* out = (float*)d_out;

    char* ws = (char*)d_ws;
    unsigned short* xseq = (unsigned short*)ws;                       // 8192*768*2 = 12582912 B
    unsigned short* wt   = (unsigned short*)(ws + 12582912);          // 512*768*2  =   786432 B
    int*            dest = (int*)(ws + 12582912 + 786432);            // 8192*4     =    32768 B

    scan_kernel<<<BATCH, SEQ, 0, stream>>>(words, dest);
    wt_kernel<<<dim3(HIDDEN / 32, EMBED / 32), 256, 0, stream>>>(wffn, wt);
    pool_kernel<<<NWORDS, 192, 0, stream>>>(words, table, dest, xseq);
    gemm_kernel<<<dim3(NWORDS / BM, EMBED / BN), 256, 0, stream>>>(xseq, wt, bffn, out);
}

// Round 2
// 162.488 us; speedup vs baseline: 1.0193x; 1.0193x over previous
//
#include <hip/hip_runtime.h>
#include <stdint.h>

#define HIDDEN 768
#define EMBED  512
#define BATCH  16
#define SEQ    512
#define NWORDS (BATCH*SEQ)      // 8192
#define PAD_FLAT_IDX 2047       // flat index of words[0, 511, 3]
#define NEG_SLOPE 0.1f

__device__ __forceinline__ unsigned short f2bf(float f) {
    unsigned int x = __float_as_uint(f);
    unsigned int r = x + 0x7fffu + ((x >> 16) & 1u);
    return (unsigned short)(r >> 16);
}

// ---------------------------------------------------------------------------
// Kernel 1 (fused prep): blocks 0..15 -> per-batch stable-compaction scan;
// blocks 16.. -> w_ffn transpose+downcast to bf16 N-major [512,768].
// 256 threads everywhere.
// ---------------------------------------------------------------------------
__global__ __launch_bounds__(256) void prep_kernel(const int* __restrict__ words,
                                                   const float* __restrict__ w,
                                                   int* __restrict__ dest,
                                                   unsigned short* __restrict__ wt) {
    if (blockIdx.x < BATCH) {
        // ---- scan: one block per batch, thread t handles words 2t, 2t+1 ----
        int b = blockIdx.x;
        int t = threadIdx.x;          // 0..255
        int s0 = 2 * t, s1 = 2 * t + 1;
        int4 wa = ((const int4*)words)[b * SEQ + s0];
        int4 wb = ((const int4*)words)[b * SEQ + s1];
        bool v0 = (wa.x | wa.y | wa.z | wa.w) != 0;
        bool v1 = (wb.x | wb.y | wb.z | wb.w) != 0;

        unsigned long long m0 = __ballot(v0);
        unsigned long long m1 = __ballot(v1);
        int lane = t & 63;
        int wave = t >> 6;            // 0..3
        unsigned long long below = (1ull << lane) - 1ull;
        int pre = __popcll(m0 & below) + __popcll(m1 & below); // valid among s<s0 in wave
        __shared__ int wsum[4];
        if (lane == 0) wsum[wave] = __popcll(m0) + __popcll(m1);
        __syncthreads();
        int off = 0, tot = 0;
#pragma unroll
        for (int i = 0; i < 4; ++i) {
            int x = wsum[i];
            if (i < wave) off += x;
            tot += x;
        }
        int vp0 = off + pre;               // # valid words before s0
        int vp1 = vp0 + (v0 ? 1 : 0);      // # valid words before s1
        int d0 = v0 ? vp0 : (tot + (s0 - vp0));
        int d1 = v1 ? vp1 : (tot + (s1 - vp1));
        dest[b * SEQ + s0] = b * SEQ + d0;
        dest[b * SEQ + s1] = b * SEQ + d1;
    } else {
        // ---- transpose: [768,512] f32 -> [512,768] bf16 ----
        __shared__ float tile[32][33];
        int bid = blockIdx.x - BATCH;       // 0..383
        int k0 = (bid % (HIDDEN / 32)) * 32;
        int n0 = (bid / (HIDDEN / 32)) * 32;
        int tc = threadIdx.x & 31;
        int tr = threadIdx.x >> 5;          // 0..7
#pragma unroll
        for (int i = 0; i < 4; ++i) {
            int r = tr + i * 8;
            tile[r][tc] = w[(size_t)(k0 + r) * EMBED + n0 + tc];
        }
        __syncthreads();
#pragma unroll
        for (int i = 0; i < 4; ++i) {
            int r = tr + i * 8;             // n offset within tile
            wt[(size_t)(n0 + r) * HIDDEN + k0 + tc] = f2bf(tile[tc][r]);
        }
    }
}

// ---------------------------------------------------------------------------
// Kernel 2: gather up to 4 embedding rows, masked mean-pool, scatter to
// compacted row as bf16. cnt==0 words get pad_vec = embed[words[0,-1,-1]].
// One block per word; 192 threads x float4 covers HIDDEN=768.
// ---------------------------------------------------------------------------
__global__ __launch_bounds__(192) void pool_kernel(const int* __restrict__ words,
                                                   const float* __restrict__ table,
                                                   const int* __restrict__ dest,
                                                   unsigned short* __restrict__ xseq) {
    int word = blockIdx.x;        // 0..8191
    int t = threadIdx.x;          // 0..191
    int drow = dest[word];        // hoisted: overlaps gather latency
    int4 w4 = ((const int4*)words)[word];
    int cnt = (w4.x != 0) + (w4.y != 0) + (w4.z != 0) + (w4.w != 0);

    float ax = 0.f, ay = 0.f, az = 0.f, aw = 0.f;
    if (cnt == 0) {
        int pid = words[PAD_FLAT_IDX];
        float4 v = ((const float4*)(table + (size_t)pid * HIDDEN))[t];
        ax = v.x; ay = v.y; az = v.z; aw = v.w;
    } else {
        if (w4.x != 0) { float4 v = ((const float4*)(table + (size_t)w4.x * HIDDEN))[t]; ax += v.x; ay += v.y; az += v.z; aw += v.w; }
        if (w4.y != 0) { float4 v = ((const float4*)(table + (size_t)w4.y * HIDDEN))[t]; ax += v.x; ay += v.y; az += v.z; aw += v.w; }
        if (w4.z != 0) { float4 v = ((const float4*)(table + (size_t)w4.z * HIDDEN))[t]; ax += v.x; ay += v.y; az += v.z; aw += v.w; }
        if (w4.w != 0) { float4 v = ((const float4*)(table + (size_t)w4.w * HIDDEN))[t]; ax += v.x; ay += v.y; az += v.z; aw += v.w; }
        float inv = 1.0f / (float)cnt;
        ax *= inv; ay *= inv; az *= inv; aw *= inv;
    }
    ushort4 o;
    o.x = f2bf(ax); o.y = f2bf(ay); o.z = f2bf(az); o.w = f2bf(aw);
    ((ushort4*)(xseq + (size_t)drow * HIDDEN))[t] = o;
}

// ---------------------------------------------------------------------------
// Kernel 3: C = leaky_relu(A @ Bt^T + bias). A=[8192,768] bf16, Bt=[512,768]
// bf16 N-major, out fp32 [8192,512].
// Tile 128(M) x 64(N) x 32(K); 256 threads = 4 waves (2x2); each wave does
// 4x2 MFMA 16x16x32 tiles (64x32). global_load_lds width=16 (m97 pattern).
// Grid 64x8 = 512 blocks -> 2 blocks/CU: cross-block overlap hides the
// vmcnt(0)+barrier drain (m114 wave-level co-scheduling).
// ---------------------------------------------------------------------------
typedef __attribute__((ext_vector_type(8))) short bf16x8;
typedef __attribute__((ext_vector_type(4))) float f32x4;

__device__ __forceinline__ void load_lds16(const void* g, void* l) {
    __builtin_amdgcn_global_load_lds(
        (const __attribute__((address_space(1))) unsigned int*)g,
        (__attribute__((address_space(3))) unsigned int*)l,
        16, 0, 0);
}

#define BM 128
#define BN 64
#define BK 32

__global__ __launch_bounds__(256) void gemm_kernel(const unsigned short* __restrict__ A,
                                                   const unsigned short* __restrict__ Bt,
                                                   const float* __restrict__ bias,
                                                   float* __restrict__ out) {
    __shared__ unsigned short sA[BM * BK];   // 8 KB
    __shared__ unsigned short sB[BN * BK];   // 4 KB

    int tid  = threadIdx.x;
    int m0   = blockIdx.x * BM;
    int n0   = blockIdx.y * BN;
    int wave = tid >> 6;
    int lane = tid & 63;
    int wr   = wave >> 1;        // 0..1: 64-row slab
    int wc   = wave & 1;         // 0..1: 32-col slab
    int quad = lane >> 4;        // 0..3
    int l16  = lane & 15;

    f32x4 acc[4][2] = {};

    // staging map: chunk c -> row c>>2, k (c&3)*8 bf16; LDS dst = c*16 B
    const unsigned short* ga0 = A  + (size_t)(m0 + (tid >> 2)) * HIDDEN + (tid & 3) * 8;
    const unsigned short* ga1 = A  + (size_t)(m0 + 64 + (tid >> 2)) * HIDDEN + (tid & 3) * 8;
    const unsigned short* gb  = Bt + (size_t)(n0 + (tid >> 2)) * HIDDEN + (tid & 3) * 8;

    for (int k0 = 0; k0 < HIDDEN; k0 += BK) {
        load_lds16(ga0 + k0, &sA[tid * 8]);
        load_lds16(ga1 + k0, &sA[(256 + tid) * 8]);
        load_lds16(gb  + k0, &sB[tid * 8]);
        __syncthreads();

        bf16x8 af[4], bf[2];
#pragma unroll
        for (int mt = 0; mt < 4; ++mt)
            af[mt] = *(const bf16x8*)&sA[(wr * 64 + mt * 16 + l16) * BK + quad * 8];
#pragma unroll
        for (int nt = 0; nt < 2; ++nt)
            bf[nt] = *(const bf16x8*)&sB[(wc * 32 + nt * 16 + l16) * BK + quad * 8];

#pragma unroll
        for (int mt = 0; mt < 4; ++mt)
#pragma unroll
            for (int nt = 0; nt < 2; ++nt)
                acc[mt][nt] = __builtin_amdgcn_mfma_f32_16x16x32_bf16(
                    af[mt], bf[nt], acc[mt][nt], 0, 0, 0);
        __syncthreads();
    }

    // epilogue: D row = quad*4+r, col = l16 (m89/m91-verified layout)
#pragma unroll
    for (int nt = 0; nt < 2; ++nt) {
        int col = n0 + wc * 32 + nt * 16 + l16;
        float bv = bias[col];
#pragma unroll
        for (int mt = 0; mt < 4; ++mt) {
            int rbase = m0 + wr * 64 + mt * 16 + quad * 4;
#pragma unroll
            for (int r = 0; r < 4; ++r) {
                float v = acc[mt][nt][r] + bv;
                v = (v > 0.f) ? v : v * NEG_SLOPE;
                out[(size_t)(rbase + r) * EMBED + col] = v;
            }
        }
    }
}

// ---------------------------------------------------------------------------
extern "C" void kernel_launch(void* const* d_in, const int* in_sizes, int n_in,
                              void* d_out, int out_size, void* d_ws, size_t ws_size,
                              hipStream_t stream) {
    (void)in_sizes; (void)n_in; (void)out_size; (void)ws_size;
    const int*   words = (const int*)d_in[0];
    const float* table = (const float*)d_in[1];
    const float* wffn  = (const float*)d_in[2];
    const float* bffn  = (const float*)d_in[3];
    float* out = (float*)d_out;

    char* ws = (char*)d_ws;
    unsigned short* xseq = (unsigned short*)ws;                       // 8192*768*2 = 12582912 B
    unsigned short* wt   = (unsigned short*)(ws + 12582912);          // 512*768*2  =   786432 B
    int*            dest = (int*)(ws + 12582912 + 786432);            // 8192*4     =    32768 B

    prep_kernel<<<BATCH + (HIDDEN / 32) * (EMBED / 32), 256, 0, stream>>>(words, wffn, dest, wt);
    pool_kernel<<<NWORDS, 192, 0, stream>>>(words, table, dest, xseq);
    gemm_kernel<<<dim3(NWORDS / BM, EMBED / BN), 256, 0, stream>>>(xseq, wt, bffn, out);
}